// Round 3
// baseline (154.622 us; speedup 1.0000x reference)
//
#include <hip/hip_runtime.h>

// Embedding gather: out[t,f,l,:] = char2vec[x[t,f,l], :]
// x: [256*256*8] int32 ids, char2vec: [8000, 64] f32, out: 33.5M f32 (134 MB).
// One thread per 16B of output -> fully coalesced stores.
// Round 3 = round 2 with native clang vector type so
// __builtin_nontemporal_store compiles (HIP_vector_type is a struct, rejected).
typedef float f32x4 __attribute__((ext_vector_type(4)));

__global__ __launch_bounds__(256) void char2vec_gather(
    const int* __restrict__ x,
    const f32x4* __restrict__ cv,      // char2vec as 16B rows: [8000][16]
    f32x4* __restrict__ out,           // [n_rows][16]
    int n4)
{
    const int g0     = blockIdx.x * blockDim.x + threadIdx.x;
    const int stride = gridDim.x * blockDim.x;
    #pragma unroll 8
    for (int i = 0; i < 16; ++i) {
        const int idx = g0 + i * stride;
        if (idx < n4) {
            const int row = idx >> 4;        // which id
            const int c   = idx & 15;        // which 16B chunk within the row
            const int id  = x[row];          // 16-lane broadcast, L1-hit
            const f32x4 v = cv[id * 16 + c]; // 256B segment, L2-resident table
            __builtin_nontemporal_store(v, &out[idx]);   // nt: don't thrash L2
        }
    }
}

extern "C" void kernel_launch(void* const* d_in, const int* in_sizes, int n_in,
                              void* d_out, int out_size, void* d_ws, size_t ws_size,
                              hipStream_t stream) {
    const int*   x  = (const int*)d_in[0];       // [256*256*8] ids
    const f32x4* cv = (const f32x4*)d_in[1];     // [8000*64] f32 viewed as 16B
    f32x4*       o  = (f32x4*)d_out;

    const int n4 = out_size / 4;                 // 8,388,608
    const int block = 256;
    // 16 chunks per thread -> grid covers n4 exactly (2048 blocks)
    int grid = (n4 + block * 16 - 1) / (block * 16);

    char2vec_gather<<<grid, block, 0, stream>>>(x, cv, o, n4);
}

// Round 5
// 143.147 us; speedup vs baseline: 1.0802x; 1.0802x over previous
//
#include <hip/hip_runtime.h>

// Embedding gather: out[t,f,l,:] = char2vec[x[t,f,l], :]
// x: [524288] int32 ids, char2vec: [8000][64] f32, out: 134 MB f32.
//
// Round 4 (resubmit after GPU-acquisition timeout): block-local structure,
// zero bounds checks.
//  - grid = 2048 blocks x 256 threads; block b owns rows [b*256, b*256+256)
//    = float4 indices [b*4096, b*4096+4096), 16 float4s per thread.
//  - 256 ids staged in LDS via ONE coalesced 1KB load (kills the 16x
//    redundant global id loads; LDS same-address reads broadcast free).
//  - thread t, iter i: row = i*16 + (t>>4), c = t&15 (compile-time affine);
//    store addr = base + i*256 + t -> each wave stores 1KB contiguous.
//  - nontemporal stores: 134 MB stream must not thrash L2 (table lives there).
typedef float f32x4 __attribute__((ext_vector_type(4)));

__global__ __launch_bounds__(256) void char2vec_gather(
    const int* __restrict__ x,
    const f32x4* __restrict__ cv,      // [8000][16] 16B chunks
    f32x4* __restrict__ out)
{
    __shared__ int ids[256];
    const int t = threadIdx.x;
    const int b = blockIdx.x;

    ids[t] = x[b * 256 + t];           // one coalesced 1KB id load per block
    __syncthreads();

    const int c    = t & 15;           // this thread's chunk within every row
    const int rsub = t >> 4;           // row offset within each 16-row group
    f32x4* obase = out + b * 4096 + t;

    #pragma unroll 8
    for (int i = 0; i < 16; ++i) {
        const int id = ids[i * 16 + rsub];         // LDS broadcast, 16 lanes
        const f32x4 v = cv[id * 16 + c];           // random 256B row, L2-hit
        __builtin_nontemporal_store(v, obase + i * 256);
    }
}

extern "C" void kernel_launch(void* const* d_in, const int* in_sizes, int n_in,
                              void* d_out, int out_size, void* d_ws, size_t ws_size,
                              hipStream_t stream) {
    const int*   x  = (const int*)d_in[0];       // [524288] ids
    const f32x4* cv = (const f32x4*)d_in[1];     // [8000*16] 16B chunks
    f32x4*       o  = (f32x4*)d_out;

    // 524288 rows / 256 rows-per-block = 2048 blocks, exact cover.
    char2vec_gather<<<2048, 256, 0, stream>>>(x, cv, o);
}